// Round 1
// baseline (751.050 us; speedup 1.0000x reference)
//
#include <hip/hip_runtime.h>
#include <math.h>

#define NB_CLASSES 1024
#define SZ_EMBED 128
#define N_SAMPLES 262144
#define MTILE 64
#define CTILE 64
#define NBLOCKS (N_SAMPLES / MTILE)  // 4096
#define XSTRIDE 136  // bf16 elems; 272B row stride -> 2-way bank alias only (free per m136)

typedef __bf16 v8bf __attribute__((ext_vector_type(8)));
typedef float v4f __attribute__((ext_vector_type(4)));

// exp(+-32*cos + 3.2) = exp2(46.166...*(+-cos) + 4.6166...)
#define EXP_A 46.16624130844683f
#define EXP_B 4.616624130844683f

// R9: latency-bound restructure.
//  - wave output 64x16 -> 32x16 over two rg passes: afrag 64->32 VGPRs,
//    freeing room for double-buffered bfrag (prefetch before MFMA block).
//  - e_acc[16] register accumulation replaces per-tile same-address LDS
//    atomics (was 4-way quad serialization, 1.57M conflict cyc/dispatch).
//    Class loop now has zero LDS ops and zero barriers.
//  - diag corrections go to tiny global atomic arrays pos_g/negd_g; pos
//    partial rows (16 MB write + 16 MB read) eliminated entirely.
#define SMEM_BYTES 19712

__device__ __forceinline__ unsigned short f2bf(float f) {
    union { float f; unsigned u; } v; v.f = f;
    unsigned u = v.u;
    unsigned rounding = 0x7FFFu + ((u >> 16) & 1u);
    return (unsigned short)((u + rounding) >> 16);
}
__device__ __forceinline__ float bfbits_lo(unsigned u) {
    union { unsigned u; float f; } v; v.u = u << 16; return v.f;
}
__device__ __forceinline__ float bfbits_hi(unsigned u) {
    union { unsigned u; float f; } v; v.u = u & 0xffff0000u; return v.f;
}

__global__ __launch_bounds__(256) void norm_proxies_kernel(
    const float* __restrict__ proxies, unsigned short* __restrict__ pn) {
    int wv = threadIdx.x >> 6;
    int lane = threadIdx.x & 63;
    int row = blockIdx.x * 4 + wv;  // grid = 256 -> rows 0..1023
    const float* src = proxies + (size_t)row * SZ_EMBED + lane * 2;
    float2 x = *(const float2*)src;
    float ss = x.x * x.x + x.y * x.y;
    #pragma unroll
    for (int off = 32; off; off >>= 1) ss += __shfl_xor(ss, off);
    float inv = rsqrtf(ss + 1e-12f);
    unsigned pk = (unsigned)f2bf(x.x * inv) | ((unsigned)f2bf(x.y * inv) << 16);
    *(unsigned*)(pn + (size_t)row * SZ_EMBED + lane * 2) = pk;
}

__global__ __launch_bounds__(256, 4) void main_kernel(
    const float* __restrict__ X, const int* __restrict__ T,
    const unsigned short* __restrict__ Pn,
    float* __restrict__ partial_neg, float* __restrict__ pos_g,
    float* __restrict__ negd_g) {
    __shared__ __align__(16) char smem[SMEM_BYTES];
    unsigned short* xtile = (unsigned short*)smem;          // 64 x 136 bf16 = 17408 B
    float (*psum)[4] = (float(*)[4])(smem + 17408);
    float (*dsum)[4] = (float(*)[4])(smem + 18432);
    int* tT = (int*)(smem + 19456);

    const int t = threadIdx.x;
    const int lane = t & 63;
    const int wv = t >> 6;
    const int quad = lane >> 4;
    const int l15 = lane & 15;
    const int sample_base = blockIdx.x * MTILE;
    const int row = t >> 2, part = t & 3;  // 4 threads per sample row, 32 cols each

    // ---- phase A: load + normalize X tile into bf16 LDS; diag dot; diag -> global atomics ----
    {
        const float4* src = (const float4*)(X + (size_t)(sample_base + row) * SZ_EMBED + part * 32);
        float4 r[8];
        float ss = 0.f;
        #pragma unroll
        for (int j = 0; j < 8; ++j) {
            r[j] = src[j];
            ss += r[j].x * r[j].x + r[j].y * r[j].y + r[j].z * r[j].z + r[j].w * r[j].w;
        }
        psum[row][part] = ss;
        if (t < MTILE) tT[t] = T[sample_base + t];
        __syncthreads();
        float inv = rsqrtf(psum[row][0] + psum[row][1] + psum[row][2] + psum[row][3] + 1e-12f);
        unsigned short* dst = xtile + row * XSTRIDE + part * 32;
        #pragma unroll
        for (int j = 0; j < 8; ++j) {
            uint2 pk;
            pk.x = (unsigned)f2bf(r[j].x * inv) | ((unsigned)f2bf(r[j].y * inv) << 16);
            pk.y = (unsigned)f2bf(r[j].z * inv) | ((unsigned)f2bf(r[j].w * inv) << 16);
            *(uint2*)(dst + j * 4) = pk;
        }
        // diag partial: dot(X[row]*inv, Pn[T[row]]) over this thread's 32 cols
        int lbl = tT[row];
        const unsigned short* prow = Pn + (size_t)lbl * SZ_EMBED + part * 32;
        float d = 0.f;
        #pragma unroll
        for (int j = 0; j < 4; ++j) {  // 4 x uint4 = 32 cols
            uint4 pv = *(const uint4*)(prow + j * 8);
            float4 xa = r[2 * j], xb = r[2 * j + 1];
            d += bfbits_lo(pv.x) * xa.x + bfbits_hi(pv.x) * xa.y;
            d += bfbits_lo(pv.y) * xa.z + bfbits_hi(pv.y) * xa.w;
            d += bfbits_lo(pv.z) * xb.x + bfbits_hi(pv.z) * xb.y;
            d += bfbits_lo(pv.w) * xb.z + bfbits_hi(pv.w) * xb.w;
        }
        dsum[row][part] = d * inv;
        __syncthreads();  // xtile + dsum ready
        if (part == 0) {
            float dd = dsum[row][0] + dsum[row][1] + dsum[row][2] + dsum[row][3];
            float dp = __builtin_amdgcn_exp2f(fmaf(dd, -EXP_A, EXP_B));  // exp(-a(cos-mrg))
            float dn = __builtin_amdgcn_exp2f(fmaf(dd,  EXP_A, EXP_B));  // exp(+a(cos+mrg))
            atomicAdd(&pos_g[lbl], dp);   // only contribution to pos sums
            atomicAdd(&negd_g[lbl], dn);  // subtracted from neg sums in finalize
        }
    }

    // ---- class loop: barrier-free, LDS-op-free. Wave (wv) owns col strip wv*16;
    // two passes over row groups rg*32 so afrag fits in 32 VGPRs. e_acc[16] holds
    // per-lane column partial sums across both passes (static indices via full unroll).
    const unsigned short* bptr = Pn + (size_t)(wv * 16 + l15) * SZ_EMBED + quad * 8;
    float e_acc[16];
    #pragma unroll
    for (int ct = 0; ct < 16; ++ct) e_acc[ct] = 0.f;

    #pragma unroll 1
    for (int rg = 0; rg < 2; ++rg) {
        v8bf afrag[2][4];
        #pragma unroll
        for (int ri = 0; ri < 2; ++ri)
            #pragma unroll
            for (int kc = 0; kc < 4; ++kc)
                afrag[ri][kc] = *(const v8bf*)(xtile + (rg * 32 + ri * 16 + l15) * XSTRIDE + kc * 32 + quad * 8);

        v8bf bfrag[2][4];
        #pragma unroll
        for (int kc = 0; kc < 4; ++kc)
            bfrag[0][kc] = *(const v8bf*)(bptr + kc * 32);

        #pragma unroll
        for (int ct = 0; ct < 16; ++ct) {
            const int cur = ct & 1, nxt = cur ^ 1;
            // prefetch next tile FIRST: L2 latency hides under 8 MFMAs + epilogue
            if (ct < 15) {
                const unsigned short* nb = bptr + (size_t)(ct + 1) * CTILE * SZ_EMBED;
                #pragma unroll
                for (int kc = 0; kc < 4; ++kc)
                    bfrag[nxt][kc] = *(const v8bf*)(nb + kc * 32);
            }
            v4f zero = {0.f, 0.f, 0.f, 0.f};
            v4f acc0 = zero, acc1 = zero;
            #pragma unroll
            for (int kc = 0; kc < 4; ++kc) {  // 2 independent chains, dep distance 2
                acc0 = __builtin_amdgcn_mfma_f32_16x16x32_bf16(afrag[0][kc], bfrag[cur][kc], acc0, 0, 0, 0);
                acc1 = __builtin_amdgcn_mfma_f32_16x16x32_bf16(afrag[1][kc], bfrag[cur][kc], acc1, 0, 0, 0);
            }
            float e[8];
            #pragma unroll
            for (int r = 0; r < 4; ++r) {
                e[r]     = __builtin_amdgcn_exp2f(fmaf(acc0[r], EXP_A, EXP_B));
                e[4 + r] = __builtin_amdgcn_exp2f(fmaf(acc1[r], EXP_A, EXP_B));
            }
            e[0] += e[4]; e[1] += e[5]; e[2] += e[6]; e[3] += e[7];
            e[0] += e[2]; e[1] += e[3];
            e_acc[ct] += e[0] + e[1];
        }
    }

    // ---- cross-quad butterfly; each class written exactly once per block: plain store ----
    float* nrow = partial_neg + (size_t)blockIdx.x * NB_CLASSES;
    #pragma unroll
    for (int ct = 0; ct < 16; ++ct) {
        float v = e_acc[ct];
        v += __shfl_xor(v, 16);
        v += __shfl_xor(v, 32);
        if (quad == 0) nrow[ct * CTILE + wv * 16 + l15] = v;
    }
}

// 256 blocks (4x the old CU coverage), neg only (half the old traffic).
// Block (g,q): sums rows [g*64, g*64+64) of class columns [q*256, q*256+256)
// into row g*64. Scalar loads: 256 consecutive threads = 1 KB contiguous/row.
__global__ __launch_bounds__(256) void row_reduce_kernel(float* __restrict__ partial_neg) {
    const int t = threadIdx.x;
    const int g = blockIdx.x >> 2, q = blockIdx.x & 3;
    float* base = partial_neg + (size_t)g * 64 * NB_CLASSES + q * 256 + t;
    float s = 0.f;
    #pragma unroll 8
    for (int r = 0; r < 64; ++r) s += base[(size_t)r * NB_CLASSES];
    base[0] = s;
}

__global__ __launch_bounds__(256) void finalize_kernel(
    const float* __restrict__ partial_neg, const float* __restrict__ pos_g,
    const float* __restrict__ negd_g, float* __restrict__ out) {
    int t = threadIdx.x;
    // surviving neg rows: {0, 64, 128, ..., 4032}
    float4 ns = {0.f, 0.f, 0.f, 0.f};
    #pragma unroll 8
    for (int r = 0; r < 64; ++r) {
        float4 vn = *(const float4*)(partial_neg + (size_t)r * 64 * NB_CLASSES + 4 * t);
        ns.x += vn.x; ns.y += vn.y; ns.z += vn.z; ns.w += vn.w;
    }
    float4 nd = *(const float4*)(negd_g + 4 * t);
    ns.x -= nd.x; ns.y -= nd.y; ns.z -= nd.z; ns.w -= nd.w;
    float4 ps = *(const float4*)(pos_g + 4 * t);
    float lp_pos = log1pf(ps.x) + log1pf(ps.y) + log1pf(ps.z) + log1pf(ps.w);
    float lp_neg = log1pf(ns.x) + log1pf(ns.y) + log1pf(ns.z) + log1pf(ns.w);
    float valid = (ps.x != 0.f) + (ps.y != 0.f) + (ps.z != 0.f) + (ps.w != 0.f);
    #pragma unroll
    for (int off = 32; off; off >>= 1) {
        lp_pos += __shfl_xor(lp_pos, off);
        lp_neg += __shfl_xor(lp_neg, off);
        valid  += __shfl_xor(valid, off);
    }
    __shared__ float s[3][4];
    int wv = t >> 6, lane = t & 63;
    if (lane == 0) { s[0][wv] = lp_pos; s[1][wv] = lp_neg; s[2][wv] = valid; }
    __syncthreads();
    if (t == 0) {
        float P = s[0][0] + s[0][1] + s[0][2] + s[0][3];
        float Ng = s[1][0] + s[1][1] + s[1][2] + s[1][3];
        float V = s[2][0] + s[2][1] + s[2][2] + s[2][3];
        float pos_term = (V > 0.f) ? (P / fmaxf(V, 1.f)) : 0.f;
        float neg_term = Ng / (float)NB_CLASSES;
        out[0] = pos_term + neg_term;
        out[1] = pos_term;
        out[2] = neg_term;
    }
}

extern "C" void kernel_launch(void* const* d_in, const int* in_sizes, int n_in,
                              void* d_out, int out_size, void* d_ws, size_t ws_size,
                              hipStream_t stream) {
    const float* X = (const float*)d_in[0];
    const float* proxies = (const float*)d_in[1];
    const int* T = (const int*)d_in[2];
    float* out = (float*)d_out;

    // ws layout: Pn (256 KB) | pos_g (4 KB) | negd_g (4 KB) | partial_neg (16 MB)
    char* ws = (char*)d_ws;
    unsigned short* Pn = (unsigned short*)ws;
    float* pos_g = (float*)(ws + (size_t)NB_CLASSES * SZ_EMBED * sizeof(unsigned short));
    float* negd_g = pos_g + NB_CLASSES;
    float* partial_neg = negd_g + NB_CLASSES;

    hipMemsetAsync(pos_g, 0, 2 * NB_CLASSES * sizeof(float), stream);
    norm_proxies_kernel<<<NB_CLASSES / 4, 256, 0, stream>>>(proxies, Pn);
    main_kernel<<<NBLOCKS, 256, 0, stream>>>(X, T, Pn, partial_neg, pos_g, negd_g);
    row_reduce_kernel<<<256, 256, 0, stream>>>(partial_neg);
    finalize_kernel<<<1, 256, 0, stream>>>(partial_neg, pos_g, negd_g, out);
}

// Round 2
// 324.612 us; speedup vs baseline: 2.3137x; 2.3137x over previous
//
#include <hip/hip_runtime.h>
#include <math.h>

#define NB_CLASSES 1024
#define SZ_EMBED 128
#define N_SAMPLES 262144
#define MTILE 64
#define CTILE 64
#define NBLOCKS (N_SAMPLES / MTILE)  // 4096
#define XSTRIDE 136  // bf16 elems; 272B row stride -> 2-way bank alias only (free per m136)

typedef __bf16 v8bf __attribute__((ext_vector_type(8)));
typedef float v4f __attribute__((ext_vector_type(4)));

// exp(+-32*cos + 3.2) = exp2(46.166...*(+-cos) + 4.6166...)
#define EXP_A 46.16624130844683f
#define EXP_B 4.616624130844683f

// R10: R9 regressed 172->625us via scratch spill (FETCH/WRITE both +860MB,
// symmetric = spill round-trip) after bfrag double-buffer + e_acc pushed
// demand past the (256,4) 128-reg cap. Revert class loop to R8's proven
// register layout (afrag[4][4]=64 resident, single bfrag[4], prefetch after
// MFMAs). Keep R9's verified zero-register-cost wins: per-ct shfl+global
// store (no LDS accumulators, no zeroing, no clobber, 2 fewer barriers),
// diag via pos_g/negd_g global atomics (16MB pos partials gone), neg-only
// 256-block row_reduce. SQ_LDS_BANK_CONFLICT identical with/without LDS
// atomics -> conflicts are phase A, not the accumulator path.
#define SMEM_BYTES 19712

__device__ __forceinline__ unsigned short f2bf(float f) {
    union { float f; unsigned u; } v; v.f = f;
    unsigned u = v.u;
    unsigned rounding = 0x7FFFu + ((u >> 16) & 1u);
    return (unsigned short)((u + rounding) >> 16);
}
__device__ __forceinline__ float bfbits_lo(unsigned u) {
    union { unsigned u; float f; } v; v.u = u << 16; return v.f;
}
__device__ __forceinline__ float bfbits_hi(unsigned u) {
    union { unsigned u; float f; } v; v.u = u & 0xffff0000u; return v.f;
}

__global__ __launch_bounds__(256) void norm_proxies_kernel(
    const float* __restrict__ proxies, unsigned short* __restrict__ pn) {
    int wv = threadIdx.x >> 6;
    int lane = threadIdx.x & 63;
    int row = blockIdx.x * 4 + wv;  // grid = 256 -> rows 0..1023
    const float* src = proxies + (size_t)row * SZ_EMBED + lane * 2;
    float2 x = *(const float2*)src;
    float ss = x.x * x.x + x.y * x.y;
    #pragma unroll
    for (int off = 32; off; off >>= 1) ss += __shfl_xor(ss, off);
    float inv = rsqrtf(ss + 1e-12f);
    unsigned pk = (unsigned)f2bf(x.x * inv) | ((unsigned)f2bf(x.y * inv) << 16);
    *(unsigned*)(pn + (size_t)row * SZ_EMBED + lane * 2) = pk;
}

__global__ __launch_bounds__(256, 4) void main_kernel(
    const float* __restrict__ X, const int* __restrict__ T,
    const unsigned short* __restrict__ Pn,
    float* __restrict__ partial_neg, float* __restrict__ pos_g,
    float* __restrict__ negd_g) {
    __shared__ __align__(16) char smem[SMEM_BYTES];
    unsigned short* xtile = (unsigned short*)smem;          // 64 x 136 bf16 = 17408 B
    float (*psum)[4] = (float(*)[4])(smem + 17408);
    float (*dsum)[4] = (float(*)[4])(smem + 18432);
    int* tT = (int*)(smem + 19456);

    const int t = threadIdx.x;
    const int lane = t & 63;
    const int wv = t >> 6;
    const int quad = lane >> 4;
    const int l15 = lane & 15;
    const int sample_base = blockIdx.x * MTILE;
    const int row = t >> 2, part = t & 3;  // 4 threads per sample row, 32 cols each

    // ---- phase A: load + normalize X tile into bf16 LDS; diag dot -> global atomics ----
    {
        const float4* src = (const float4*)(X + (size_t)(sample_base + row) * SZ_EMBED + part * 32);
        float4 r[8];
        float ss = 0.f;
        #pragma unroll
        for (int j = 0; j < 8; ++j) {
            r[j] = src[j];
            ss += r[j].x * r[j].x + r[j].y * r[j].y + r[j].z * r[j].z + r[j].w * r[j].w;
        }
        psum[row][part] = ss;
        if (t < MTILE) tT[t] = T[sample_base + t];
        __syncthreads();
        float inv = rsqrtf(psum[row][0] + psum[row][1] + psum[row][2] + psum[row][3] + 1e-12f);
        unsigned short* dst = xtile + row * XSTRIDE + part * 32;
        #pragma unroll
        for (int j = 0; j < 8; ++j) {
            uint2 pk;
            pk.x = (unsigned)f2bf(r[j].x * inv) | ((unsigned)f2bf(r[j].y * inv) << 16);
            pk.y = (unsigned)f2bf(r[j].z * inv) | ((unsigned)f2bf(r[j].w * inv) << 16);
            *(uint2*)(dst + j * 4) = pk;
        }
        // diag partial: dot(X[row]*inv, Pn[T[row]]) over this thread's 32 cols
        int lbl = tT[row];
        const unsigned short* prow = Pn + (size_t)lbl * SZ_EMBED + part * 32;
        float d = 0.f;
        #pragma unroll
        for (int j = 0; j < 4; ++j) {  // 4 x uint4 = 32 cols
            uint4 pv = *(const uint4*)(prow + j * 8);
            float4 xa = r[2 * j], xb = r[2 * j + 1];
            d += bfbits_lo(pv.x) * xa.x + bfbits_hi(pv.x) * xa.y;
            d += bfbits_lo(pv.y) * xa.z + bfbits_hi(pv.y) * xa.w;
            d += bfbits_lo(pv.z) * xb.x + bfbits_hi(pv.z) * xb.y;
            d += bfbits_lo(pv.w) * xb.z + bfbits_hi(pv.w) * xb.w;
        }
        dsum[row][part] = d * inv;
        __syncthreads();  // xtile + dsum ready; xtile never clobbered after this
        if (part == 0) {
            int lbl2 = tT[row];
            float dd = dsum[row][0] + dsum[row][1] + dsum[row][2] + dsum[row][3];
            float dp = __builtin_amdgcn_exp2f(fmaf(dd, -EXP_A, EXP_B));  // exp(-a(cos-mrg))
            float dn = __builtin_amdgcn_exp2f(fmaf(dd,  EXP_A, EXP_B));  // exp(+a(cos+mrg))
            atomicAdd(&pos_g[lbl2], dp);   // only contribution to pos sums
            atomicAdd(&negd_g[lbl2], dn);  // subtracted from neg sums in finalize
        }
    }

    // ---- extract A fragments into registers (resident for whole class loop) ----
    v8bf afrag[4][4];
    #pragma unroll
    for (int ri = 0; ri < 4; ++ri)
        #pragma unroll
        for (int kc = 0; kc < 4; ++kc)
            afrag[ri][kc] = *(const v8bf*)(xtile + (ri * 16 + l15) * XSTRIDE + kc * 32 + quad * 8);

    // ---- class loop: barrier-free, LDS-op-free. Wave wv owns col strip wv*16+l15
    // of each 64-class tile. Single-buffered bfrag (R8 layout, no spill): MFMAs
    // consume, then prefetch next tile, then epilogue covers the L2 latency.
    const unsigned short* bptr = Pn + (size_t)(wv * 16 + l15) * SZ_EMBED + quad * 8;
    v8bf bfrag[4];
    #pragma unroll
    for (int kc = 0; kc < 4; ++kc)
        bfrag[kc] = *(const v8bf*)(bptr + kc * 32);

    float* nrow = partial_neg + (size_t)blockIdx.x * NB_CLASSES + wv * 16 + l15;

    #pragma unroll
    for (int ct = 0; ct < NB_CLASSES / CTILE; ++ct) {
        v4f zero = {0.f, 0.f, 0.f, 0.f};
        v4f acc[4] = {zero, zero, zero, zero};
        #pragma unroll
        for (int kc = 0; kc < 4; ++kc)
            #pragma unroll
            for (int ri = 0; ri < 4; ++ri)
                acc[ri] = __builtin_amdgcn_mfma_f32_16x16x32_bf16(afrag[ri][kc], bfrag[kc], acc[ri], 0, 0, 0);

        // issue next tile's loads (bfrag fully consumed above); epilogue hides latency
        if (ct < NB_CLASSES / CTILE - 1) {
            const unsigned short* nb = bptr + (size_t)(ct + 1) * CTILE * SZ_EMBED;
            #pragma unroll
            for (int kc = 0; kc < 4; ++kc)
                bfrag[kc] = *(const v8bf*)(nb + kc * 32);
        }

        // epilogue: exp2 per element, pairwise tree (16 rows/lane), cross-quad
        // butterfly (rows 0..63), one plain 4B store per quad-0 lane.
        float e[16];
        #pragma unroll
        for (int ri = 0; ri < 4; ++ri)
            #pragma unroll
            for (int r = 0; r < 4; ++r)
                e[ri * 4 + r] = __builtin_amdgcn_exp2f(fmaf(acc[ri][r], EXP_A, EXP_B));
        #pragma unroll
        for (int s = 8; s; s >>= 1)
            #pragma unroll
            for (int j = 0; j < s; ++j)
                e[j] += e[j + s];
        float v = e[0];
        v += __shfl_xor(v, 16);
        v += __shfl_xor(v, 32);
        if (quad == 0) nrow[ct * CTILE] = v;
    }
}

// 256 blocks, neg only. Block (g,q): sums rows [g*64, g*64+64) of class
// columns [q*256, q*256+256) into row g*64. 256 threads = 1 KB contiguous/row.
__global__ __launch_bounds__(256) void row_reduce_kernel(float* __restrict__ partial_neg) {
    const int t = threadIdx.x;
    const int g = blockIdx.x >> 2, q = blockIdx.x & 3;
    float* base = partial_neg + (size_t)g * 64 * NB_CLASSES + q * 256 + t;
    float s = 0.f;
    #pragma unroll 8
    for (int r = 0; r < 64; ++r) s += base[(size_t)r * NB_CLASSES];
    base[0] = s;
}

__global__ __launch_bounds__(256) void finalize_kernel(
    const float* __restrict__ partial_neg, const float* __restrict__ pos_g,
    const float* __restrict__ negd_g, float* __restrict__ out) {
    int t = threadIdx.x;
    // surviving neg rows: {0, 64, 128, ..., 4032}
    float4 ns = {0.f, 0.f, 0.f, 0.f};
    #pragma unroll 8
    for (int r = 0; r < 64; ++r) {
        float4 vn = *(const float4*)(partial_neg + (size_t)r * 64 * NB_CLASSES + 4 * t);
        ns.x += vn.x; ns.y += vn.y; ns.z += vn.z; ns.w += vn.w;
    }
    float4 nd = *(const float4*)(negd_g + 4 * t);
    ns.x -= nd.x; ns.y -= nd.y; ns.z -= nd.z; ns.w -= nd.w;
    float4 ps = *(const float4*)(pos_g + 4 * t);
    float lp_pos = log1pf(ps.x) + log1pf(ps.y) + log1pf(ps.z) + log1pf(ps.w);
    float lp_neg = log1pf(ns.x) + log1pf(ns.y) + log1pf(ns.z) + log1pf(ns.w);
    float valid = (ps.x != 0.f) + (ps.y != 0.f) + (ps.z != 0.f) + (ps.w != 0.f);
    #pragma unroll
    for (int off = 32; off; off >>= 1) {
        lp_pos += __shfl_xor(lp_pos, off);
        lp_neg += __shfl_xor(lp_neg, off);
        valid  += __shfl_xor(valid, off);
    }
    __shared__ float s[3][4];
    int wv = t >> 6, lane = t & 63;
    if (lane == 0) { s[0][wv] = lp_pos; s[1][wv] = lp_neg; s[2][wv] = valid; }
    __syncthreads();
    if (t == 0) {
        float P = s[0][0] + s[0][1] + s[0][2] + s[0][3];
        float Ng = s[1][0] + s[1][1] + s[1][2] + s[1][3];
        float V = s[2][0] + s[2][1] + s[2][2] + s[2][3];
        float pos_term = (V > 0.f) ? (P / fmaxf(V, 1.f)) : 0.f;
        float neg_term = Ng / (float)NB_CLASSES;
        out[0] = pos_term + neg_term;
        out[1] = pos_term;
        out[2] = neg_term;
    }
}

extern "C" void kernel_launch(void* const* d_in, const int* in_sizes, int n_in,
                              void* d_out, int out_size, void* d_ws, size_t ws_size,
                              hipStream_t stream) {
    const float* X = (const float*)d_in[0];
    const float* proxies = (const float*)d_in[1];
    const int* T = (const int*)d_in[2];
    float* out = (float*)d_out;

    // ws layout: Pn (256 KB) | pos_g (4 KB) | negd_g (4 KB) | partial_neg (16 MB)
    char* ws = (char*)d_ws;
    unsigned short* Pn = (unsigned short*)ws;
    float* pos_g = (float*)(ws + (size_t)NB_CLASSES * SZ_EMBED * sizeof(unsigned short));
    float* negd_g = pos_g + NB_CLASSES;
    float* partial_neg = negd_g + NB_CLASSES;

    hipMemsetAsync(pos_g, 0, 2 * NB_CLASSES * sizeof(float), stream);
    norm_proxies_kernel<<<NB_CLASSES / 4, 256, 0, stream>>>(proxies, Pn);
    main_kernel<<<NBLOCKS, 256, 0, stream>>>(X, T, Pn, partial_neg, pos_g, negd_g);
    row_reduce_kernel<<<256, 256, 0, stream>>>(partial_neg);
    finalize_kernel<<<1, 256, 0, stream>>>(partial_neg, pos_g, negd_g, out);
}